// Round 1
// baseline (488.658 us; speedup 1.0000x reference)
//
#include <hip/hip_runtime.h>
#include <math.h>

#define EPS 1e-6f

constexpr int B = 8, C = 3, H = 720, W = 1280;
// log2(1.414) computed in double precision
constexpr float K_LOG2 = 0.49978254377554356f;

__global__ void init_min_kernel(unsigned int* p) {
    *p = 0x7F7FFFFFu;  // FLT_MAX bit pattern (ws is poisoned 0xAA each call)
}

// Global min of disp. All disp >= 0 so uint bit-pattern ordering == float ordering.
__global__ __launch_bounds__(256) void min_kernel(const float* __restrict__ disp,
                                                  unsigned int* __restrict__ out,
                                                  int n4) {
    int tid = blockIdx.x * blockDim.x + threadIdx.x;
    int stride = gridDim.x * blockDim.x;
    float m = 3.4e38f;
    const float4* d4 = (const float4*)disp;
    for (int i = tid; i < n4; i += stride) {
        float4 v = d4[i];
        m = fminf(m, fminf(fminf(v.x, v.y), fminf(v.z, v.w)));
    }
    // wave=64 shuffle reduction
    #pragma unroll
    for (int off = 32; off > 0; off >>= 1)
        m = fminf(m, __shfl_down(m, off, 64));
    if ((threadIdx.x & 63) == 0)
        atomicMin(out, __float_as_uint(m));
}

// One block per (b, y) row. 1-D splat accumulated in LDS, then normalize + store.
__global__ __launch_bounds__(256) void splat_kernel(const float* __restrict__ im,
                                                    const float* __restrict__ disp,
                                                    const unsigned int* __restrict__ minbits,
                                                    float* __restrict__ out) {
    __shared__ float acc0[W];
    __shared__ float acc1[W];
    __shared__ float acc2[W];
    __shared__ float accw[W];

    const int row = blockIdx.x;        // 0 .. B*H-1
    const int b = row / H;
    const int y = row - b * H;

    const float dmin = __uint_as_float(*minbits);

    for (int x = threadIdx.x; x < W; x += blockDim.x) {
        acc0[x] = 0.0f; acc1[x] = 0.0f; acc2[x] = 0.0f; accw[x] = 0.0f;
    }
    __syncthreads();

    const float* __restrict__ dr  = disp + (size_t)row * W;                 // disp[b,0,y,:]
    const float* __restrict__ im0 = im + ((size_t)(b * C + 0) * H + y) * W; // im[b,0,y,:]
    const float* __restrict__ im1 = im + ((size_t)(b * C + 1) * H + y) * W;
    const float* __restrict__ im2 = im + ((size_t)(b * C + 2) * H + y) * W;

    for (int x = threadIdx.x; x < W; x += blockDim.x) {
        float d = dr[x];
        float w = exp2f(K_LOG2 * (d - dmin));  // 1.414^(d - dmin)
        float tx = (float)x - d;
        float x0f = floorf(tx);
        int   x0  = (int)x0f;
        float wc  = tx - x0f;          // weight toward x0+1
        float wa  = (x0f + 1.0f) - tx; // weight toward x0
        float v0 = im0[x] * w;
        float v1 = im1[x] * w;
        float v2 = im2[x] * w;
        if (x0 >= 0 && x0 < W) {
            atomicAdd(&acc0[x0], wa * v0);
            atomicAdd(&acc1[x0], wa * v1);
            atomicAdd(&acc2[x0], wa * v2);
            atomicAdd(&accw[x0], wa * w);
        }
        int x1 = x0 + 1;
        if (x1 >= 0 && x1 < W) {
            atomicAdd(&acc0[x1], wc * v0);
            atomicAdd(&acc1[x1], wc * v1);
            atomicAdd(&acc2[x1], wc * v2);
            atomicAdd(&accw[x1], wc * w);
        }
    }
    __syncthreads();

    float* __restrict__ o0 = out + ((size_t)(b * C + 0) * H + y) * W;
    float* __restrict__ o1 = out + ((size_t)(b * C + 1) * H + y) * W;
    float* __restrict__ o2 = out + ((size_t)(b * C + 2) * H + y) * W;
    for (int x = threadIdx.x; x < W; x += blockDim.x) {
        float mw = fmaxf(accw[x], EPS);
        float inv = 1.0f / mw;
        o0[x] = acc0[x] * inv;
        o1[x] = acc1[x] * inv;
        o2[x] = acc2[x] * inv;
    }
}

extern "C" void kernel_launch(void* const* d_in, const int* in_sizes, int n_in,
                              void* d_out, int out_size, void* d_ws, size_t ws_size,
                              hipStream_t stream) {
    const float* im   = (const float*)d_in[0];
    const float* disp = (const float*)d_in[1];
    float* out = (float*)d_out;
    unsigned int* minbits = (unsigned int*)d_ws;

    init_min_kernel<<<1, 1, 0, stream>>>(minbits);

    const int n4 = (B * H * W) / 4;  // disp is [B,1,H,W]
    min_kernel<<<1024, 256, 0, stream>>>(disp, minbits, n4);

    splat_kernel<<<B * H, 256, 0, stream>>>(im, disp, minbits, out);
}